// Round 9
// baseline (507.299 us; speedup 1.0000x reference)
//
#include <hip/hip_runtime.h>
#include <math.h>

namespace {

typedef __attribute__((ext_vector_type(8))) short short8;
typedef __attribute__((ext_vector_type(4))) float f32x4;
typedef __attribute__((ext_vector_type(2))) float f32x2;

constexpr int B  = 2;
constexpr int C  = 256;
constexpr int NH = 8;
constexpr int L  = 4;
constexpr int P  = 4;
constexpr int D  = 32;
constexpr int LV = 13294;
constexpr int LQ = 13294;
constexpr int M  = B * LQ;      // 26588 rows for all GEMMs

constexpr int SZ[4]    = {100, 50, 25, 13};
constexpr int START[4] = {0, 10000, 12500, 13125};

constexpr int RS = 264;                   // LDS B row stride (shorts)

__device__ inline short bf16r(float f) {    // RTNE f32 -> bf16
  unsigned u = __float_as_uint(f);
  u += 0x7fff + ((u >> 16) & 1);
  return (short)(u >> 16);
}

// 8 x f32 -> short8 bf16 via v_cvt_pk_bf16_f32 (RTNE, 1 instr / 2 elems).
__device__ inline short8 cvt8(const f32x4 lo, const f32x4 hi) {
  union { uint4 u; short8 s; } r;
  asm("v_cvt_pk_bf16_f32 %0, %1, %2" : "=v"(r.u.x) : "v"(lo[0]), "v"(lo[1]));
  asm("v_cvt_pk_bf16_f32 %0, %1, %2" : "=v"(r.u.y) : "v"(lo[2]), "v"(lo[3]));
  asm("v_cvt_pk_bf16_f32 %0, %1, %2" : "=v"(r.u.z) : "v"(hi[0]), "v"(hi[1]));
  asm("v_cvt_pk_bf16_f32 %0, %1, %2" : "=v"(r.u.w) : "v"(hi[2]), "v"(hi[3]));
  return r.s;
}

// A-fragment load straight from the f32 (len,B,C) tensor, converting
// in-register (no staging round-trip).
__device__ inline void load_a_cvt(const float* __restrict__ arow, short8 a[8]) {
#pragma unroll
  for (int s = 0; s < 8; ++s) {
    const f32x4 lo = *reinterpret_cast<const f32x4*>(arow + s * 32);
    const f32x4 hi = *reinterpret_cast<const f32x4*>(arow + s * 32 + 4);
    a[s] = cvt8(lo, hi);
  }
}

__device__ inline void load_a_bf16(const unsigned short* __restrict__ arow, short8 a[8]) {
#pragma unroll
  for (int s = 0; s < 8; ++s)
    a[s] = *reinterpret_cast<const short8*>(arow + s * 32);
}

// ---------------------------------------------------------------------------
// k_pre: weight transpose/convert only (W[k][n] -> Bt[n][k] bf16).
// ---------------------------------------------------------------------------
__global__ __launch_bounds__(256) void k_pre(
    const float* __restrict__ Wv, const float* __restrict__ Woff,
    const float* __restrict__ Wattn, const float* __restrict__ Wo,
    unsigned short* __restrict__ Btv, unsigned short* __restrict__ Btoa,
    unsigned short* __restrict__ Bto) {
  __shared__ float tile[32][33];
  const int blk = blockIdx.x;
  const float* src; unsigned short* dst; int N, local;
  if (blk < 64)       { src = Wv;    dst = Btv;              N = 256; local = blk; }
  else if (blk < 128) { src = Woff;  dst = Btoa;             N = 256; local = blk - 64; }
  else if (blk < 160) { src = Wattn; dst = Btoa + 256 * 256; N = 128; local = blk - 128; }
  else                { src = Wo;    dst = Bto;              N = 256; local = blk - 160; }
  const int ntiles = N >> 5;
  const int kt = local / ntiles, nt = local - kt * ntiles;
  const int k0 = kt << 5, n0 = nt << 5;
  const int tx = threadIdx.x & 31, ty = threadIdx.x >> 5;
#pragma unroll
  for (int r = 0; r < 4; ++r) {
    const int kk = ty + r * 8;
    tile[kk][tx] = src[(size_t)(k0 + kk) * N + n0 + tx];
  }
  __syncthreads();
#pragma unroll
  for (int r = 0; r < 4; ++r) {
    const int nn = ty + r * 8;
    dst[(size_t)(n0 + nn) * 256 + k0 + tx] = (unsigned short)bf16r(tile[tx][nn]);
  }
}

// ---------------------------------------------------------------------------
// GEMM core. R9: register-prefetch B staging — chunk ch+1 is global-loaded
// into registers WHILE chunk ch computes; the inter-barrier stage phase is
// now pure ds_write (global latency hidden under MFMA). 64-row M-tiles
// (R8 grid: 832 blocks, ~3.25/CU).
//   blockIdx.y == 0: value x Wv        (N=256, 4 chunks) -> val (bf16)
//   blockIdx.y == 1: query x Woff/attn (N=384, 6 chunks) -> loc, attn
// ---------------------------------------------------------------------------
__global__ __launch_bounds__(256, 4) void k_gemm12(
    const float* __restrict__ query, const float* __restrict__ value,
    const float* __restrict__ rp,
    const unsigned short* __restrict__ Btv, const unsigned short* __restrict__ Btoa,
    const float* __restrict__ bv, const float* __restrict__ boff,
    const float* __restrict__ battn,
    unsigned short* __restrict__ val, float* __restrict__ loc,
    float* __restrict__ attn) {
  __shared__ unsigned short sB[64 * RS];    // 33.8 KB, refilled per chunk
  __shared__ float sRP[64][9];              // 2.3 KB clamped rp cache (y=1)
  const int tid = threadIdx.x;
  const int wave = tid >> 6, lane = tid & 63, quad = lane >> 4, lo = lane & 15;
  const bool isval = (blockIdx.y == 0);
  const float* __restrict__ Af = isval ? value : query;
  const unsigned short* Bt  = isval ? Btv : Btoa;
  const int NC = isval ? 4 : 6;
  const int m0 = blockIdx.x * 64;
  const int mrow = m0 + wave * 16;          // this wave's 16 output rows

  // Per-thread B-chunk slice coordinates (8 uint4 per thread per chunk).
  const int brow0 = tid >> 5, bcc = (tid & 31) * 8;

  // A: load + convert once (full K=256 resident in registers).
  short8 a[8];
  {
    const int mr = min(mrow + lo, M - 1);
    const int bb = mr / LQ, ii = mr - bb * LQ;    // source layout (len, B, C)
    load_a_cvt(Af + ((size_t)(ii * 2 + bb)) * 256 + quad * 8, a);
  }

  if (!isval && tid < 128) {
    // Stage clamped rp rows for this M-tile: 64 rows x 8 floats, 2 thr/row.
    const int r = tid >> 1, q4 = (tid & 1) * 4;
    const int mr = min(m0 + r, M - 1);
    f32x4 v = *reinterpret_cast<const f32x4*>(rp + (size_t)mr * 8 + q4);
#pragma unroll
    for (int j = 0; j < 4; ++j) v[j] = fminf(fmaxf(v[j], 1e-5f), 1.f - 1e-5f);
    *reinterpret_cast<f32x4*>(&sRP[r][q4]) = v;
  }

  // Prefetch chunk 0 into registers.
  uint4 breg[8];
#pragma unroll
  for (int i = 0; i < 8; ++i)
    breg[i] = *reinterpret_cast<const uint4*>(
        Bt + (((size_t)(brow0 + i * 8)) << 8) + bcc);

#pragma unroll 1
  for (int ch = 0; ch < NC; ++ch) {
    __syncthreads();   // previous chunk's compute done with sB (also fences sRP)
    // Commit prefetched chunk to LDS (pure ds_write — no global latency here).
#pragma unroll
    for (int i = 0; i < 8; ++i)
      *reinterpret_cast<uint4*>(&sB[(brow0 + i * 8) * RS + bcc]) = breg[i];
    // Issue next chunk's global loads; latency overlaps this chunk's MFMAs.
    if (ch + 1 < NC) {
      const int n1 = (ch + 1) * 64;
#pragma unroll
      for (int i = 0; i < 8; ++i)
        breg[i] = *reinterpret_cast<const uint4*>(
            Bt + (((size_t)(n1 + brow0 + i * 8)) << 8) + bcc);
    }
    __syncthreads();

    const int n0 = ch * 64;
#pragma unroll 1
    for (int tt = 0; tt < 4; ++tt) {
      const unsigned short* bsrc = &sB[(tt * 16 + lo) * RS + quad * 8];
      short8 b[8];
#pragma unroll
      for (int s = 0; s < 8; ++s)
        b[s] = *reinterpret_cast<const short8*>(bsrc + s * 32);
      f32x4 acc = (f32x4){0.f, 0.f, 0.f, 0.f};
#pragma unroll
      for (int s = 0; s < 8; ++s)
        acc = __builtin_amdgcn_mfma_f32_16x16x32_bf16(b[s], a[s], acc, 0, 0, 0);

      const int nb = n0 + tt * 16 + quad * 4;   // this lane's 4 consecutive cols
      const int m = mrow + lo;
      if (isval) {
        const f32x4 bias4 = *reinterpret_cast<const f32x4*>(bv + nb);
        const int h = nb >> 5, d0 = nb & 31;
        if (m < M) {
          const int bb = m / LV, i = m - bb * LV;
          ushort4 o;
          o.x = (unsigned short)bf16r(acc[0] + bias4[0]);
          o.y = (unsigned short)bf16r(acc[1] + bias4[1]);
          o.z = (unsigned short)bf16r(acc[2] + bias4[2]);
          o.w = (unsigned short)bf16r(acc[3] + bias4[3]);
          *reinterpret_cast<ushort4*>(
              val + (((size_t)(bb * NH + h)) * LV + i) * D + d0) = o;
        }
      } else if (ch < 4) {                      // nb < 256: offsets -> loc
        const f32x4 bias4 = *reinterpret_cast<const f32x4*>(boff + nb);
        const int l = (nb >> 3) & 3;
        const float rsz = (l == 0) ? 0.01f : (l == 1) ? 0.02f
                        : (l == 2) ? 0.04f : (1.f / 13.f);
        if (m < M) {
          const int lr = wave * 16 + lo;        // row in sRP
          const float rx = sRP[lr][l * 2];
          const float ry = sRP[lr][l * 2 + 1];
          f32x4 o;
          o[0] = fmaf(acc[0] + bias4[0], rsz, rx);
          o[1] = fmaf(acc[1] + bias4[1], rsz, ry);
          o[2] = fmaf(acc[2] + bias4[2], rsz, rx);
          o[3] = fmaf(acc[3] + bias4[3], rsz, ry);
          *reinterpret_cast<f32x4*>(loc + (size_t)m * 256 + nb) = o;
        }
      } else {                                  // attention logits -> softmax
        const int n2 = nb - 256;                // head*16 + 4-aligned col
        const f32x4 bias4 = *reinterpret_cast<const f32x4*>(battn + n2);
        float v0 = acc[0] + bias4[0], v1 = acc[1] + bias4[1];
        float v2 = acc[2] + bias4[2], v3 = acc[3] + bias4[3];
        float mx = fmaxf(fmaxf(v0, v1), fmaxf(v2, v3));
        mx = fmaxf(mx, __shfl_xor(mx, 16, 64));
        mx = fmaxf(mx, __shfl_xor(mx, 32, 64));
        const float e0 = __expf(v0 - mx), e1 = __expf(v1 - mx);
        const float e2 = __expf(v2 - mx), e3 = __expf(v3 - mx);
        float s = e0 + e1 + e2 + e3;
        s += __shfl_xor(s, 16, 64);
        s += __shfl_xor(s, 32, 64);
        const float inv = 1.f / s;
        if (m < M) {
          f32x4 o; o[0] = e0 * inv; o[1] = e1 * inv; o[2] = e2 * inv; o[3] = e3 * inv;
          *reinterpret_cast<f32x4*>(attn + (size_t)m * 128 + n2) = o;
        }
      }
    }
  }
}

// ---------------------------------------------------------------------------
// GEMM 3 (R9: same register-prefetch B staging): out = tmp @ Wo + bo + query.
// ---------------------------------------------------------------------------
__global__ __launch_bounds__(256, 4) void k_gemm3(
    const unsigned short* __restrict__ tmp, const float* __restrict__ query,
    const unsigned short* __restrict__ Bt, const float* __restrict__ bo,
    float* __restrict__ out) {
  __shared__ unsigned short sB[64 * RS];    // 33.8 KB
  const int tid = threadIdx.x;
  const int wave = tid >> 6, lane = tid & 63, quad = lane >> 4, lo = lane & 15;
  const int m0 = blockIdx.x * 64;
  const int mrow = m0 + wave * 16;
  const int brow0 = tid >> 5, bcc = (tid & 31) * 8;

  short8 a[8];
  {
    const int mr = min(mrow + lo, M - 1);
    load_a_bf16(tmp + (size_t)mr * 256 + quad * 8, a);
  }

  uint4 breg[8];
#pragma unroll
  for (int i = 0; i < 8; ++i)
    breg[i] = *reinterpret_cast<const uint4*>(
        Bt + (((size_t)(brow0 + i * 8)) << 8) + bcc);

#pragma unroll 1
  for (int ch = 0; ch < 4; ++ch) {
    __syncthreads();
#pragma unroll
    for (int i = 0; i < 8; ++i)
      *reinterpret_cast<uint4*>(&sB[(brow0 + i * 8) * RS + bcc]) = breg[i];
    if (ch + 1 < 4) {
      const int n1 = (ch + 1) * 64;
#pragma unroll
      for (int i = 0; i < 8; ++i)
        breg[i] = *reinterpret_cast<const uint4*>(
            Bt + (((size_t)(n1 + brow0 + i * 8)) << 8) + bcc);
    }
    __syncthreads();

    const int n0 = ch * 64;
#pragma unroll 1
    for (int tt = 0; tt < 4; ++tt) {
      const unsigned short* bsrc = &sB[(tt * 16 + lo) * RS + quad * 8];
      short8 b[8];
#pragma unroll
      for (int s = 0; s < 8; ++s)
        b[s] = *reinterpret_cast<const short8*>(bsrc + s * 32);
      f32x4 acc = (f32x4){0.f, 0.f, 0.f, 0.f};
#pragma unroll
      for (int s = 0; s < 8; ++s)
        acc = __builtin_amdgcn_mfma_f32_16x16x32_bf16(b[s], a[s], acc, 0, 0, 0);
      const int nb = n0 + tt * 16 + quad * 4;
      const f32x4 bias4 = *reinterpret_cast<const f32x4*>(bo + nb);
      const int m = mrow + lo;
      if (m < M) {
        const int bb = m / LQ, q = m - bb * LQ;
        const size_t o = ((size_t)(q * B + bb)) * C + nb;
        const f32x4 qv = *reinterpret_cast<const f32x4*>(query + o);
        f32x4 ov;
        ov[0] = acc[0] + bias4[0] + qv[0];
        ov[1] = acc[1] + bias4[1] + qv[1];
        ov[2] = acc[2] + bias4[2] + qv[2];
        ov[3] = acc[3] + bias4[3] + qv[3];
        *reinterpret_cast<f32x4*>(out + o) = ov;
      }
    }
  }
}

// ---------------------------------------------------------------------------
// Bilinear sampling + attention weighting. R9: launch_bounds(256,8) —
// VGPR=60 already fits the 64-reg budget for 8 waves/SIMD; the old (256,4)
// bound was self-capping occupancy at 50% (measured 33-35%). LDS 12.8 KB x
// 8 blocks = 102 KB < 160. Code otherwise byte-identical to R6/R8.
// ---------------------------------------------------------------------------
#define QB_I(v, PAT) __builtin_amdgcn_ds_swizzle((v), (PAT))
#define QB_F(v, PAT) __int_as_float(__builtin_amdgcn_ds_swizzle(__float_as_int(v), (PAT)))

__device__ inline void msda_corner(f32x2 acc[4], const uint4 r, const float w) {
  const f32x2 wv = {w, w};
  f32x2 v;
  v[0] = __uint_as_float(r.x << 16);
  v[1] = __uint_as_float(r.x & 0xffff0000u);
  acc[0] = __builtin_elementwise_fma(v, wv, acc[0]);
  v[0] = __uint_as_float(r.y << 16);
  v[1] = __uint_as_float(r.y & 0xffff0000u);
  acc[1] = __builtin_elementwise_fma(v, wv, acc[1]);
  v[0] = __uint_as_float(r.z << 16);
  v[1] = __uint_as_float(r.z & 0xffff0000u);
  acc[2] = __builtin_elementwise_fma(v, wv, acc[2]);
  v[0] = __uint_as_float(r.w << 16);
  v[1] = __uint_as_float(r.w & 0xffff0000u);
  acc[3] = __builtin_elementwise_fma(v, wv, acc[3]);
}

__global__ __launch_bounds__(256, 8) void k_sample(
    const unsigned short* __restrict__ val, const float* __restrict__ loc,
    const float* __restrict__ attn, unsigned short* __restrict__ tmp) {
  constexpr int QPB = 8;
  const int mblk = blockIdx.x * QPB;
  const int t = threadIdx.x;
  __shared__ float sloc[QPB * 8 * 33];    // [q][h][33]
  __shared__ float sattn[QPB * 8 * 17];   // [q][h][17]
  for (int i = t; i < QPB * 256; i += 256) {
    int mq = mblk + (i >> 8); if (mq >= M) mq = M - 1;
    const int j = i & 255;
    sloc[(((i >> 8) << 3) + (j >> 5)) * 33 + (j & 31)] = loc[(size_t)mq * 256 + j];
  }
  for (int i = t; i < QPB * 128; i += 256) {
    int mq = mblk + (i >> 7); if (mq >= M) mq = M - 1;
    const int j = i & 127;
    sattn[(((i >> 7) << 3) + (j >> 4)) * 17 + (j & 15)] = attn[(size_t)mq * 128 + j];
  }
  __syncthreads();

  const int g = t >> 5, s = t & 31, h = s >> 2, c8 = s & 3;
  const int m = mblk + g;
  const int mc = (m < M) ? m : M - 1;
  const int b = mc / LQ;
  const unsigned short* vhead = val + ((size_t)(b * NH + h) * LV) * D + c8 * 8;
  const float* ql = sloc + (g * 8 + h) * 33;
  const float* qa = sattn + (g * 8 + h) * 17;

  f32x2 acc[4];
  acc[0] = (f32x2){0.f, 0.f}; acc[1] = (f32x2){0.f, 0.f};
  acc[2] = (f32x2){0.f, 0.f}; acc[3] = (f32x2){0.f, 0.f};
#pragma unroll 1
  for (int l = 0; l < L; ++l) {
    const int Wl = SZ[l];
    const float Wlf = (float)Wl;
    const unsigned short* vlev = vhead + (size_t)START[l] * D;
    // Own point: p = c8. (Each quad lane computes one point's geometry.)
    const float x = ql[l * 8 + c8 * 2]     * Wlf - 0.5f;
    const float y = ql[l * 8 + c8 * 2 + 1] * Wlf - 0.5f;
    const float aw = qa[l * 4 + c8];
    const float x0f = floorf(x), y0f = floorf(y);
    const float wx = x - x0f, wy = y - y0f;
    const int x0 = (int)x0f, y0 = (int)y0f;
    const int x1 = x0 + 1, y1 = y0 + 1;
    const float wy1v = wy * aw;
    const float wy0m = ((unsigned)y0 < (unsigned)Wl) ? (aw - wy1v) : 0.f;
    const float wy1m = ((unsigned)y1 < (unsigned)Wl) ? wy1v : 0.f;
    const float wx0m = ((unsigned)x0 < (unsigned)Wl) ? (1.f - wx) : 0.f;
    const float wx1m = ((unsigned)x1 < (unsigned)Wl) ? wx : 0.f;
    const int xc0 = min(max(x0, 0), Wl - 1), xc1 = min(max(x1, 0), Wl - 1);
    const int yc0 = min(max(y0, 0), Wl - 1), yc1 = min(max(y1, 0), Wl - 1);
    const int r0 = yc0 * Wl, r1 = yc1 * Wl;
    const int o00 = (r0 + xc0) * D, o01 = (r0 + xc1) * D;
    const int o10 = (r1 + xc0) * D, o11 = (r1 + xc1) * D;
    const float w00 = wy0m * wx0m, w01 = wy0m * wx1m;
    const float w10 = wy1m * wx0m, w11 = wy1m * wx1m;

    // Phase 1: broadcast all 16 offsets + weights (quad-perm).
    int   off[16];
    float ww[16];
#define MSDA_BCAST(P, PAT)                                                \
    off[(P)*4+0] = QB_I(o00, PAT); off[(P)*4+1] = QB_I(o01, PAT);         \
    off[(P)*4+2] = QB_I(o10, PAT); off[(P)*4+3] = QB_I(o11, PAT);         \
    ww[(P)*4+0]  = QB_F(w00, PAT); ww[(P)*4+1]  = QB_F(w01, PAT);         \
    ww[(P)*4+2]  = QB_F(w10, PAT); ww[(P)*4+3]  = QB_F(w11, PAT);
    MSDA_BCAST(0, 0x8000)   // p=0: sel 0,0,0,0
    MSDA_BCAST(1, 0x8055)   // p=1: sel 1,1,1,1
    MSDA_BCAST(2, 0x80AA)   // p=2: sel 2,2,2,2
    MSDA_BCAST(3, 0x80FF)   // p=3: sel 3,3,3,3
#undef MSDA_BCAST

    // Phase 2: issue all 16 gathers (stay in flight together).
    uint4 v[16];
#pragma unroll
    for (int i = 0; i < 16; ++i)
      v[i] = *reinterpret_cast<const uint4*>(vlev + off[i]);

    // Phase 3: consume in identical point/corner order.
#pragma unroll
    for (int i = 0; i < 16; ++i)
      msda_corner(acc, v[i], ww[i]);
  }
  if (m < M) {
    short8 o;
#pragma unroll
    for (int j = 0; j < 4; ++j) {
      o[2 * j]     = bf16r(acc[j][0]);
      o[2 * j + 1] = bf16r(acc[j][1]);
    }
    *reinterpret_cast<short8*>(tmp + (size_t)m * 256 + h * 32 + c8 * 8) = o;
  }
}

}  // namespace

extern "C" void kernel_launch(void* const* d_in, const int* in_sizes, int n_in,
                              void* d_out, int out_size, void* d_ws, size_t ws_size,
                              hipStream_t stream) {
  const float* query = (const float*)d_in[0];
  const float* rp    = (const float*)d_in[1];
  const float* value = (const float*)d_in[2];
  const float* Wv    = (const float*)d_in[5];
  const float* bv    = (const float*)d_in[6];
  const float* Woff  = (const float*)d_in[7];
  const float* boff  = (const float*)d_in[8];
  const float* Wattn = (const float*)d_in[9];
  const float* battn = (const float*)d_in[10];
  const float* Wo    = (const float*)d_in[11];
  const float* bo    = (const float*)d_in[12];
  float* out = (float*)d_out;

  unsigned short* Btv  = (unsigned short*)d_ws;        // 256*256
  unsigned short* Btoa = Btv + 256 * 256;              // 384*256
  unsigned short* Bto  = Btoa + 384 * 256;             // 256*256
  unsigned short* val  = Bto + 256 * 256;              // M*256 bf16
  float* loc  = (float*)(val + (size_t)M * 256);       // M*256 f32
  float* attn = loc + (size_t)M * 256;                 // M*128 f32
  unsigned short* tmp = (unsigned short*)(attn + (size_t)M * 128);  // M*256 bf16

  const int mtiles64 = (M + 63) / 64;                  // 416
  const int sample_blocks = (M + 7) / 8;               // 3324

  k_pre<<<224, 256, 0, stream>>>(Wv, Woff, Wattn, Wo, Btv, Btoa, Bto);
  k_gemm12<<<dim3(mtiles64, 2), 256, 0, stream>>>(query, value, rp, Btv, Btoa,
                                                  bv, boff, battn, val, loc, attn);
  k_sample<<<sample_blocks, 256, 0, stream>>>(val, loc, attn, tmp);
  k_gemm3<<<mtiles64, 256, 0, stream>>>(tmp, query, Bto, bo, out);
}

// Round 10
// 210.443 us; speedup vs baseline: 2.4106x; 2.4106x over previous
//
#include <hip/hip_runtime.h>
#include <math.h>

namespace {

typedef __attribute__((ext_vector_type(8))) short short8;
typedef __attribute__((ext_vector_type(4))) float f32x4;
typedef __attribute__((ext_vector_type(2))) float f32x2;

constexpr int B  = 2;
constexpr int C  = 256;
constexpr int NH = 8;
constexpr int L  = 4;
constexpr int P  = 4;
constexpr int D  = 32;
constexpr int LV = 13294;
constexpr int LQ = 13294;
constexpr int M  = B * LQ;      // 26588 rows for all GEMMs

constexpr int SZ[4]    = {100, 50, 25, 13};
constexpr int START[4] = {0, 10000, 12500, 13125};

constexpr int RS = 264;                   // LDS B row stride (shorts)

__device__ inline short bf16r(float f) {    // RTNE f32 -> bf16
  unsigned u = __float_as_uint(f);
  u += 0x7fff + ((u >> 16) & 1);
  return (short)(u >> 16);
}

// 8 x f32 -> short8 bf16 via v_cvt_pk_bf16_f32 (RTNE, 1 instr / 2 elems).
__device__ inline short8 cvt8(const f32x4 lo, const f32x4 hi) {
  union { uint4 u; short8 s; } r;
  asm("v_cvt_pk_bf16_f32 %0, %1, %2" : "=v"(r.u.x) : "v"(lo[0]), "v"(lo[1]));
  asm("v_cvt_pk_bf16_f32 %0, %1, %2" : "=v"(r.u.y) : "v"(lo[2]), "v"(lo[3]));
  asm("v_cvt_pk_bf16_f32 %0, %1, %2" : "=v"(r.u.z) : "v"(hi[0]), "v"(hi[1]));
  asm("v_cvt_pk_bf16_f32 %0, %1, %2" : "=v"(r.u.w) : "v"(hi[2]), "v"(hi[3]));
  return r.s;
}

// A-fragment load straight from the f32 (len,B,C) tensor, converting
// in-register (no staging round-trip).
__device__ inline void load_a_cvt(const float* __restrict__ arow, short8 a[8]) {
#pragma unroll
  for (int s = 0; s < 8; ++s) {
    const f32x4 lo = *reinterpret_cast<const f32x4*>(arow + s * 32);
    const f32x4 hi = *reinterpret_cast<const f32x4*>(arow + s * 32 + 4);
    a[s] = cvt8(lo, hi);
  }
}

__device__ inline void load_a_bf16(const unsigned short* __restrict__ arow, short8 a[8]) {
#pragma unroll
  for (int s = 0; s < 8; ++s)
    a[s] = *reinterpret_cast<const short8*>(arow + s * 32);
}

// ---------------------------------------------------------------------------
// k_pre: weight transpose/convert only (W[k][n] -> Bt[n][k] bf16).
// ---------------------------------------------------------------------------
__global__ __launch_bounds__(256) void k_pre(
    const float* __restrict__ Wv, const float* __restrict__ Woff,
    const float* __restrict__ Wattn, const float* __restrict__ Wo,
    unsigned short* __restrict__ Btv, unsigned short* __restrict__ Btoa,
    unsigned short* __restrict__ Bto) {
  __shared__ float tile[32][33];
  const int blk = blockIdx.x;
  const float* src; unsigned short* dst; int N, local;
  if (blk < 64)       { src = Wv;    dst = Btv;              N = 256; local = blk; }
  else if (blk < 128) { src = Woff;  dst = Btoa;             N = 256; local = blk - 64; }
  else if (blk < 160) { src = Wattn; dst = Btoa + 256 * 256; N = 128; local = blk - 128; }
  else                { src = Wo;    dst = Bto;              N = 256; local = blk - 160; }
  const int ntiles = N >> 5;
  const int kt = local / ntiles, nt = local - kt * ntiles;
  const int k0 = kt << 5, n0 = nt << 5;
  const int tx = threadIdx.x & 31, ty = threadIdx.x >> 5;
#pragma unroll
  for (int r = 0; r < 4; ++r) {
    const int kk = ty + r * 8;
    tile[kk][tx] = src[(size_t)(k0 + kk) * N + n0 + tx];
  }
  __syncthreads();
#pragma unroll
  for (int r = 0; r < 4; ++r) {
    const int nn = ty + r * 8;
    dst[(size_t)(n0 + nn) * 256 + k0 + tx] = (unsigned short)bf16r(tile[tx][nn]);
  }
}

// ---------------------------------------------------------------------------
// GEMM core. R10: extend the proven R7->R8 lever (block count) — N-chunks
// split across grid-y. Each block: 64 M-rows x 2 chunks (128 cols).
// gemm12 grid (416,5) = 2080 blocks (~8/CU supply, LDS-capped residency 4):
//   y=0,1   -> val panels   (chunks 2y, 2y+1 of Wv,  N=256)
//   y=2,3,4 -> offattn panels (chunks 2(y-2), ... of Woff/Wattn, N=384)
// A re-read x2/x3 (+82 MB) — proven free in this latency-bound regime (R3).
// Internals byte-identical to R8 (reg-prefetch reverted after R9 spill).
// ---------------------------------------------------------------------------
__global__ __launch_bounds__(256, 4) void k_gemm12(
    const float* __restrict__ query, const float* __restrict__ value,
    const float* __restrict__ rp,
    const unsigned short* __restrict__ Btv, const unsigned short* __restrict__ Btoa,
    const float* __restrict__ bv, const float* __restrict__ boff,
    const float* __restrict__ battn,
    unsigned short* __restrict__ val, float* __restrict__ loc,
    float* __restrict__ attn) {
  __shared__ unsigned short sB[64 * RS];    // 33.8 KB, refilled per chunk
  __shared__ float sRP[64][9];              // 2.3 KB clamped rp cache (y>=2)
  const int tid = threadIdx.x;
  const int wave = tid >> 6, lane = tid & 63, quad = lane >> 4, lo = lane & 15;
  const int y = blockIdx.y;
  const bool isval = (y < 2);
  const int panel = isval ? y : y - 2;
  const float* __restrict__ Af = isval ? value : query;
  const unsigned short* Bt  = isval ? Btv : Btoa;
  const int m0 = blockIdx.x * 64;
  const int mrow = m0 + wave * 16;          // this wave's 16 output rows

  // A: load + convert once (full K=256 resident in registers).
  short8 a[8];
  {
    const int mr = min(mrow + lo, M - 1);
    const int bb = mr / LQ, ii = mr - bb * LQ;    // source layout (len, B, C)
    load_a_cvt(Af + ((size_t)(ii * 2 + bb)) * 256 + quad * 8, a);
  }

  if (!isval && tid < 128) {
    // Stage clamped rp rows for this M-tile: 64 rows x 8 floats, 2 thr/row.
    const int r = tid >> 1, q4 = (tid & 1) * 4;
    const int mr = min(m0 + r, M - 1);
    f32x4 v = *reinterpret_cast<const f32x4*>(rp + (size_t)mr * 8 + q4);
#pragma unroll
    for (int j = 0; j < 4; ++j) v[j] = fminf(fmaxf(v[j], 1e-5f), 1.f - 1e-5f);
    *reinterpret_cast<f32x4*>(&sRP[r][q4]) = v;
  }

#pragma unroll 1
  for (int ch2 = 0; ch2 < 2; ++ch2) {
    const int ch = panel * 2 + ch2;           // global chunk index
    const int n0 = ch * 64;
    __syncthreads();   // previous chunk's compute done with sB (also fences sRP)
    // Stage B chunk: 64 rows x 512 B = 2048 uint4, 8/thread, coalesced.
#pragma unroll
    for (int i = 0; i < 8; ++i) {
      const int cid = i * 256 + tid;
      const int row = cid >> 5, cc = cid & 31;
      const uint4 v = *reinterpret_cast<const uint4*>(Bt + (((size_t)(n0 + row)) << 8) + cc * 8);
      *reinterpret_cast<uint4*>(&sB[row * RS + cc * 8]) = v;
    }
    __syncthreads();

#pragma unroll 1
    for (int tt = 0; tt < 4; ++tt) {
      const unsigned short* bsrc = &sB[(tt * 16 + lo) * RS + quad * 8];
      short8 b[8];
#pragma unroll
      for (int s = 0; s < 8; ++s)
        b[s] = *reinterpret_cast<const short8*>(bsrc + s * 32);
      f32x4 acc = (f32x4){0.f, 0.f, 0.f, 0.f};
#pragma unroll
      for (int s = 0; s < 8; ++s)
        acc = __builtin_amdgcn_mfma_f32_16x16x32_bf16(b[s], a[s], acc, 0, 0, 0);

      const int nb = n0 + tt * 16 + quad * 4;   // this lane's 4 consecutive cols
      const int m = mrow + lo;
      if (isval) {
        const f32x4 bias4 = *reinterpret_cast<const f32x4*>(bv + nb);
        const int h = nb >> 5, d0 = nb & 31;
        if (m < M) {
          const int bb = m / LV, i = m - bb * LV;
          ushort4 o;
          o.x = (unsigned short)bf16r(acc[0] + bias4[0]);
          o.y = (unsigned short)bf16r(acc[1] + bias4[1]);
          o.z = (unsigned short)bf16r(acc[2] + bias4[2]);
          o.w = (unsigned short)bf16r(acc[3] + bias4[3]);
          *reinterpret_cast<ushort4*>(
              val + (((size_t)(bb * NH + h)) * LV + i) * D + d0) = o;
        }
      } else if (ch < 4) {                      // nb < 256: offsets -> loc
        const f32x4 bias4 = *reinterpret_cast<const f32x4*>(boff + nb);
        const int l = (nb >> 3) & 3;
        const float rsz = (l == 0) ? 0.01f : (l == 1) ? 0.02f
                        : (l == 2) ? 0.04f : (1.f / 13.f);
        if (m < M) {
          const int lr = wave * 16 + lo;        // row in sRP
          const float rx = sRP[lr][l * 2];
          const float ry = sRP[lr][l * 2 + 1];
          f32x4 o;
          o[0] = fmaf(acc[0] + bias4[0], rsz, rx);
          o[1] = fmaf(acc[1] + bias4[1], rsz, ry);
          o[2] = fmaf(acc[2] + bias4[2], rsz, rx);
          o[3] = fmaf(acc[3] + bias4[3], rsz, ry);
          *reinterpret_cast<f32x4*>(loc + (size_t)m * 256 + nb) = o;
        }
      } else {                                  // attention logits -> softmax
        const int n2 = nb - 256;                // head*16 + 4-aligned col
        const f32x4 bias4 = *reinterpret_cast<const f32x4*>(battn + n2);
        float v0 = acc[0] + bias4[0], v1 = acc[1] + bias4[1];
        float v2 = acc[2] + bias4[2], v3 = acc[3] + bias4[3];
        float mx = fmaxf(fmaxf(v0, v1), fmaxf(v2, v3));
        mx = fmaxf(mx, __shfl_xor(mx, 16, 64));
        mx = fmaxf(mx, __shfl_xor(mx, 32, 64));
        const float e0 = __expf(v0 - mx), e1 = __expf(v1 - mx);
        const float e2 = __expf(v2 - mx), e3 = __expf(v3 - mx);
        float s = e0 + e1 + e2 + e3;
        s += __shfl_xor(s, 16, 64);
        s += __shfl_xor(s, 32, 64);
        const float inv = 1.f / s;
        if (m < M) {
          f32x4 o; o[0] = e0 * inv; o[1] = e1 * inv; o[2] = e2 * inv; o[3] = e3 * inv;
          *reinterpret_cast<f32x4*>(attn + (size_t)m * 128 + n2) = o;
        }
      }
    }
  }
}

// ---------------------------------------------------------------------------
// GEMM 3 (R10: grid (416,2), each block 64 M-rows x 2 chunks):
// out = tmp @ Wo + bo + query.
// ---------------------------------------------------------------------------
__global__ __launch_bounds__(256, 4) void k_gemm3(
    const unsigned short* __restrict__ tmp, const float* __restrict__ query,
    const unsigned short* __restrict__ Bt, const float* __restrict__ bo,
    float* __restrict__ out) {
  __shared__ unsigned short sB[64 * RS];    // 33.8 KB
  const int tid = threadIdx.x;
  const int wave = tid >> 6, lane = tid & 63, quad = lane >> 4, lo = lane & 15;
  const int m0 = blockIdx.x * 64;
  const int mrow = m0 + wave * 16;
  const int panel = blockIdx.y;

  short8 a[8];
  {
    const int mr = min(mrow + lo, M - 1);
    load_a_bf16(tmp + (size_t)mr * 256 + quad * 8, a);
  }

#pragma unroll 1
  for (int ch2 = 0; ch2 < 2; ++ch2) {
    const int n0 = (panel * 2 + ch2) * 64;
    __syncthreads();
#pragma unroll
    for (int i = 0; i < 8; ++i) {
      const int cid = i * 256 + tid;
      const int row = cid >> 5, cc = cid & 31;
      const uint4 v = *reinterpret_cast<const uint4*>(Bt + (((size_t)(n0 + row)) << 8) + cc * 8);
      *reinterpret_cast<uint4*>(&sB[row * RS + cc * 8]) = v;
    }
    __syncthreads();

#pragma unroll 1
    for (int tt = 0; tt < 4; ++tt) {
      const unsigned short* bsrc = &sB[(tt * 16 + lo) * RS + quad * 8];
      short8 b[8];
#pragma unroll
      for (int s = 0; s < 8; ++s)
        b[s] = *reinterpret_cast<const short8*>(bsrc + s * 32);
      f32x4 acc = (f32x4){0.f, 0.f, 0.f, 0.f};
#pragma unroll
      for (int s = 0; s < 8; ++s)
        acc = __builtin_amdgcn_mfma_f32_16x16x32_bf16(b[s], a[s], acc, 0, 0, 0);
      const int nb = n0 + tt * 16 + quad * 4;
      const f32x4 bias4 = *reinterpret_cast<const f32x4*>(bo + nb);
      const int m = mrow + lo;
      if (m < M) {
        const int bb = m / LQ, q = m - bb * LQ;
        const size_t o = ((size_t)(q * B + bb)) * C + nb;
        const f32x4 qv = *reinterpret_cast<const f32x4*>(query + o);
        f32x4 ov;
        ov[0] = acc[0] + bias4[0] + qv[0];
        ov[1] = acc[1] + bias4[1] + qv[1];
        ov[2] = acc[2] + bias4[2] + qv[2];
        ov[3] = acc[3] + bias4[3] + qv[3];
        *reinterpret_cast<f32x4*>(out + o) = ov;
      }
    }
  }
}

// ---------------------------------------------------------------------------
// Bilinear sampling + attention weighting — EXACT R8 version (the R9
// launch_bounds(256,8) forced a 64-VGPR budget and spilled v[16] to
// scratch: WRITE_SIZE 13->741 MB, dur 55->277 us. (256,4) is correct.)
// ---------------------------------------------------------------------------
#define QB_I(v, PAT) __builtin_amdgcn_ds_swizzle((v), (PAT))
#define QB_F(v, PAT) __int_as_float(__builtin_amdgcn_ds_swizzle(__float_as_int(v), (PAT)))

__device__ inline void msda_corner(f32x2 acc[4], const uint4 r, const float w) {
  const f32x2 wv = {w, w};
  f32x2 v;
  v[0] = __uint_as_float(r.x << 16);
  v[1] = __uint_as_float(r.x & 0xffff0000u);
  acc[0] = __builtin_elementwise_fma(v, wv, acc[0]);
  v[0] = __uint_as_float(r.y << 16);
  v[1] = __uint_as_float(r.y & 0xffff0000u);
  acc[1] = __builtin_elementwise_fma(v, wv, acc[1]);
  v[0] = __uint_as_float(r.z << 16);
  v[1] = __uint_as_float(r.z & 0xffff0000u);
  acc[2] = __builtin_elementwise_fma(v, wv, acc[2]);
  v[0] = __uint_as_float(r.w << 16);
  v[1] = __uint_as_float(r.w & 0xffff0000u);
  acc[3] = __builtin_elementwise_fma(v, wv, acc[3]);
}

__global__ __launch_bounds__(256, 4) void k_sample(
    const unsigned short* __restrict__ val, const float* __restrict__ loc,
    const float* __restrict__ attn, unsigned short* __restrict__ tmp) {
  constexpr int QPB = 8;
  const int mblk = blockIdx.x * QPB;
  const int t = threadIdx.x;
  __shared__ float sloc[QPB * 8 * 33];    // [q][h][33]
  __shared__ float sattn[QPB * 8 * 17];   // [q][h][17]
  for (int i = t; i < QPB * 256; i += 256) {
    int mq = mblk + (i >> 8); if (mq >= M) mq = M - 1;
    const int j = i & 255;
    sloc[(((i >> 8) << 3) + (j >> 5)) * 33 + (j & 31)] = loc[(size_t)mq * 256 + j];
  }
  for (int i = t; i < QPB * 128; i += 256) {
    int mq = mblk + (i >> 7); if (mq >= M) mq = M - 1;
    const int j = i & 127;
    sattn[(((i >> 7) << 3) + (j >> 4)) * 17 + (j & 15)] = attn[(size_t)mq * 128 + j];
  }
  __syncthreads();

  const int g = t >> 5, s = t & 31, h = s >> 2, c8 = s & 3;
  const int m = mblk + g;
  const int mc = (m < M) ? m : M - 1;
  const int b = mc / LQ;
  const unsigned short* vhead = val + ((size_t)(b * NH + h) * LV) * D + c8 * 8;
  const float* ql = sloc + (g * 8 + h) * 33;
  const float* qa = sattn + (g * 8 + h) * 17;

  f32x2 acc[4];
  acc[0] = (f32x2){0.f, 0.f}; acc[1] = (f32x2){0.f, 0.f};
  acc[2] = (f32x2){0.f, 0.f}; acc[3] = (f32x2){0.f, 0.f};
#pragma unroll 1
  for (int l = 0; l < L; ++l) {
    const int Wl = SZ[l];
    const float Wlf = (float)Wl;
    const unsigned short* vlev = vhead + (size_t)START[l] * D;
    // Own point: p = c8. (Each quad lane computes one point's geometry.)
    const float x = ql[l * 8 + c8 * 2]     * Wlf - 0.5f;
    const float y = ql[l * 8 + c8 * 2 + 1] * Wlf - 0.5f;
    const float aw = qa[l * 4 + c8];
    const float x0f = floorf(x), y0f = floorf(y);
    const float wx = x - x0f, wy = y - y0f;
    const int x0 = (int)x0f, y0 = (int)y0f;
    const int x1 = x0 + 1, y1 = y0 + 1;
    const float wy1v = wy * aw;
    const float wy0m = ((unsigned)y0 < (unsigned)Wl) ? (aw - wy1v) : 0.f;
    const float wy1m = ((unsigned)y1 < (unsigned)Wl) ? wy1v : 0.f;
    const float wx0m = ((unsigned)x0 < (unsigned)Wl) ? (1.f - wx) : 0.f;
    const float wx1m = ((unsigned)x1 < (unsigned)Wl) ? wx : 0.f;
    const int xc0 = min(max(x0, 0), Wl - 1), xc1 = min(max(x1, 0), Wl - 1);
    const int yc0 = min(max(y0, 0), Wl - 1), yc1 = min(max(y1, 0), Wl - 1);
    const int r0 = yc0 * Wl, r1 = yc1 * Wl;
    const int o00 = (r0 + xc0) * D, o01 = (r0 + xc1) * D;
    const int o10 = (r1 + xc0) * D, o11 = (r1 + xc1) * D;
    const float w00 = wy0m * wx0m, w01 = wy0m * wx1m;
    const float w10 = wy1m * wx0m, w11 = wy1m * wx1m;

    // Phase 1: broadcast all 16 offsets + weights (quad-perm).
    int   off[16];
    float ww[16];
#define MSDA_BCAST(P, PAT)                                                \
    off[(P)*4+0] = QB_I(o00, PAT); off[(P)*4+1] = QB_I(o01, PAT);         \
    off[(P)*4+2] = QB_I(o10, PAT); off[(P)*4+3] = QB_I(o11, PAT);         \
    ww[(P)*4+0]  = QB_F(w00, PAT); ww[(P)*4+1]  = QB_F(w01, PAT);         \
    ww[(P)*4+2]  = QB_F(w10, PAT); ww[(P)*4+3]  = QB_F(w11, PAT);
    MSDA_BCAST(0, 0x8000)   // p=0: sel 0,0,0,0
    MSDA_BCAST(1, 0x8055)   // p=1: sel 1,1,1,1
    MSDA_BCAST(2, 0x80AA)   // p=2: sel 2,2,2,2
    MSDA_BCAST(3, 0x80FF)   // p=3: sel 3,3,3,3
#undef MSDA_BCAST

    // Phase 2: issue all 16 gathers (stay in flight together).
    uint4 v[16];
#pragma unroll
    for (int i = 0; i < 16; ++i)
      v[i] = *reinterpret_cast<const uint4*>(vlev + off[i]);

    // Phase 3: consume in identical point/corner order.
#pragma unroll
    for (int i = 0; i < 16; ++i)
      msda_corner(acc, v[i], ww[i]);
  }
  if (m < M) {
    short8 o;
#pragma unroll
    for (int j = 0; j < 4; ++j) {
      o[2 * j]     = bf16r(acc[j][0]);
      o[2 * j + 1] = bf16r(acc[j][1]);
    }
    *reinterpret_cast<short8*>(tmp + (size_t)m * 256 + h * 32 + c8 * 8) = o;
  }
}

}  // namespace

extern "C" void kernel_launch(void* const* d_in, const int* in_sizes, int n_in,
                              void* d_out, int out_size, void* d_ws, size_t ws_size,
                              hipStream_t stream) {
  const float* query = (const float*)d_in[0];
  const float* rp    = (const float*)d_in[1];
  const float* value = (const float*)d_in[2];
  const float* Wv    = (const float*)d_in[5];
  const float* bv    = (const float*)d_in[6];
  const float* Woff  = (const float*)d_in[7];
  const float* boff  = (const float*)d_in[8];
  const float* Wattn = (const float*)d_in[9];
  const float* battn = (const float*)d_in[10];
  const float* Wo    = (const float*)d_in[11];
  const float* bo    = (const float*)d_in[12];
  float* out = (float*)d_out;

  unsigned short* Btv  = (unsigned short*)d_ws;        // 256*256
  unsigned short* Btoa = Btv + 256 * 256;              // 384*256
  unsigned short* Bto  = Btoa + 384 * 256;             // 256*256
  unsigned short* val  = Bto + 256 * 256;              // M*256 bf16
  float* loc  = (float*)(val + (size_t)M * 256);       // M*256 f32
  float* attn = loc + (size_t)M * 256;                 // M*128 f32
  unsigned short* tmp = (unsigned short*)(attn + (size_t)M * 128);  // M*256 bf16

  const int mtiles64 = (M + 63) / 64;                  // 416
  const int sample_blocks = (M + 7) / 8;               // 3324

  k_pre<<<224, 256, 0, stream>>>(Wv, Woff, Wattn, Wo, Btv, Btoa, Bto);
  k_gemm12<<<dim3(mtiles64, 5), 256, 0, stream>>>(query, value, rp, Btv, Btoa,
                                                  bv, boff, battn, val, loc, attn);
  k_sample<<<sample_blocks, 256, 0, stream>>>(val, loc, attn, tmp);
  k_gemm3<<<dim3(mtiles64, 2), 256, 0, stream>>>(tmp, query, Bto, bo, out);
}

// Round 11
// 203.608 us; speedup vs baseline: 2.4915x; 1.0336x over previous
//
#include <hip/hip_runtime.h>
#include <math.h>

namespace {

typedef __attribute__((ext_vector_type(8))) short short8;
typedef __attribute__((ext_vector_type(4))) float f32x4;
typedef __attribute__((ext_vector_type(2))) float f32x2;

constexpr int B  = 2;
constexpr int C  = 256;
constexpr int NH = 8;
constexpr int L  = 4;
constexpr int P  = 4;
constexpr int D  = 32;
constexpr int LV = 13294;
constexpr int LQ = 13294;
constexpr int M  = B * LQ;      // 26588 rows for all GEMMs

constexpr int SZ[4]    = {100, 50, 25, 13};
constexpr int START[4] = {0, 10000, 12500, 13125};

__device__ inline short bf16r(float f) {    // RTNE f32 -> bf16
  unsigned u = __float_as_uint(f);
  u += 0x7fff + ((u >> 16) & 1);
  return (short)(u >> 16);
}

// 8 x f32 -> short8 bf16 via v_cvt_pk_bf16_f32 (RTNE, 1 instr / 2 elems).
__device__ inline short8 cvt8(const f32x4 lo, const f32x4 hi) {
  union { uint4 u; short8 s; } r;
  asm("v_cvt_pk_bf16_f32 %0, %1, %2" : "=v"(r.u.x) : "v"(lo[0]), "v"(lo[1]));
  asm("v_cvt_pk_bf16_f32 %0, %1, %2" : "=v"(r.u.y) : "v"(lo[2]), "v"(lo[3]));
  asm("v_cvt_pk_bf16_f32 %0, %1, %2" : "=v"(r.u.z) : "v"(hi[0]), "v"(hi[1]));
  asm("v_cvt_pk_bf16_f32 %0, %1, %2" : "=v"(r.u.w) : "v"(hi[2]), "v"(hi[3]));
  return r.s;
}

// A-fragment load straight from the f32 (len,B,C) tensor, converting
// in-register (no staging round-trip).
__device__ inline void load_a_cvt(const float* __restrict__ arow, short8 a[8]) {
#pragma unroll
  for (int s = 0; s < 8; ++s) {
    const f32x4 lo = *reinterpret_cast<const f32x4*>(arow + s * 32);
    const f32x4 hi = *reinterpret_cast<const f32x4*>(arow + s * 32 + 4);
    a[s] = cvt8(lo, hi);
  }
}

__device__ inline void load_a_bf16(const unsigned short* __restrict__ arow, short8 a[8]) {
#pragma unroll
  for (int s = 0; s < 8; ++s)
    a[s] = *reinterpret_cast<const short8*>(arow + s * 32);
}

// Direct global->LDS DMA, 16 B/lane (wave-uniform LDS base + lane*16).
__device__ inline void glds16(const unsigned short* g, unsigned short* l) {
  __builtin_amdgcn_global_load_lds(
      (const __attribute__((address_space(1))) void*)g,
      (__attribute__((address_space(3))) void*)l, 16, 0, 0);
}

// ---------------------------------------------------------------------------
// k_pre: weight transpose/convert (W[k][n] -> Bt[n][k] bf16), now storing
// each 512 B row XOR-SWIZZLED: k_phys = k ^ ((n&7)<<3)  (16B slot index
// XOR'd with row&7). This lets the GEMMs stage chunks as pure linear
// copies via global_load_lds (unpadded LDS) while the swizzled ds_read
// keeps the b128 fragment loads at the padded layout's conflict floor.
// ---------------------------------------------------------------------------
__global__ __launch_bounds__(256) void k_pre(
    const float* __restrict__ Wv, const float* __restrict__ Woff,
    const float* __restrict__ Wattn, const float* __restrict__ Wo,
    unsigned short* __restrict__ Btv, unsigned short* __restrict__ Btoa,
    unsigned short* __restrict__ Bto) {
  __shared__ float tile[32][33];
  const int blk = blockIdx.x;
  const float* src; unsigned short* dst; int N, local;
  if (blk < 64)       { src = Wv;    dst = Btv;              N = 256; local = blk; }
  else if (blk < 128) { src = Woff;  dst = Btoa;             N = 256; local = blk - 64; }
  else if (blk < 160) { src = Wattn; dst = Btoa + 256 * 256; N = 128; local = blk - 128; }
  else                { src = Wo;    dst = Bto;              N = 256; local = blk - 160; }
  const int ntiles = N >> 5;
  const int kt = local / ntiles, nt = local - kt * ntiles;
  const int k0 = kt << 5, n0 = nt << 5;
  const int tx = threadIdx.x & 31, ty = threadIdx.x >> 5;
#pragma unroll
  for (int r = 0; r < 4; ++r) {
    const int kk = ty + r * 8;
    tile[kk][tx] = src[(size_t)(k0 + kk) * N + n0 + tx];
  }
  __syncthreads();
#pragma unroll
  for (int r = 0; r < 4; ++r) {
    const int nn = ty + r * 8;
    const int n = n0 + nn, k = k0 + tx;
    dst[(size_t)n * 256 + (k ^ ((n & 7) << 3))] = (unsigned short)bf16r(tile[tx][nn]);
  }
}

// ---------------------------------------------------------------------------
// GEMM core (R8 grid/structure). R11: B-chunk staging via global_load_lds —
// the chunk is a linear 32 KB copy (swizzle baked into Bt by k_pre), LDS
// unpadded [64][256]; b-fragment ds_read applies the same XOR on its slot
// index. Replaces 8 loads + 8 stores per thread with 8 async DMA ops.
//   blockIdx.y == 0: value x Wv        (N=256, 4 chunks) -> val (bf16)
//   blockIdx.y == 1: query x Woff/attn (N=384, 6 chunks) -> loc, attn
// ---------------------------------------------------------------------------
__global__ __launch_bounds__(256, 4) void k_gemm12(
    const float* __restrict__ query, const float* __restrict__ value,
    const float* __restrict__ rp,
    const unsigned short* __restrict__ Btv, const unsigned short* __restrict__ Btoa,
    const float* __restrict__ bv, const float* __restrict__ boff,
    const float* __restrict__ battn,
    unsigned short* __restrict__ val, float* __restrict__ loc,
    float* __restrict__ attn) {
  __shared__ unsigned short sB[64 * 256];   // 32 KB, linear (swizzled content)
  __shared__ float sRP[64][9];              // 2.3 KB clamped rp cache (y=1)
  const int tid = threadIdx.x;
  const int wave = tid >> 6, lane = tid & 63, quad = lane >> 4, lo = lane & 15;
  const bool isval = (blockIdx.y == 0);
  const float* __restrict__ Af = isval ? value : query;
  const unsigned short* Bt  = isval ? Btv : Btoa;
  const int NC = isval ? 4 : 6;
  const int m0 = blockIdx.x * 64;
  const int mrow = m0 + wave * 16;          // this wave's 16 output rows

  // A: load + convert once (full K=256 resident in registers).
  short8 a[8];
  {
    const int mr = min(mrow + lo, M - 1);
    const int bb = mr / LQ, ii = mr - bb * LQ;    // source layout (len, B, C)
    load_a_cvt(Af + ((size_t)(ii * 2 + bb)) * 256 + quad * 8, a);
  }

  if (!isval && tid < 128) {
    // Stage clamped rp rows for this M-tile: 64 rows x 8 floats, 2 thr/row.
    const int r = tid >> 1, q4 = (tid & 1) * 4;
    const int mr = min(m0 + r, M - 1);
    f32x4 v = *reinterpret_cast<const f32x4*>(rp + (size_t)mr * 8 + q4);
#pragma unroll
    for (int j = 0; j < 4; ++j) v[j] = fminf(fmaxf(v[j], 1e-5f), 1.f - 1e-5f);
    *reinterpret_cast<f32x4*>(&sRP[r][q4]) = v;
  }

  const int sw = lo & 7;                    // ds_read slot XOR (row&7)

#pragma unroll 1
  for (int ch = 0; ch < NC; ++ch) {
    const int n0 = ch * 64;
    __syncthreads();   // previous chunk's compute done with sB (also fences sRP)
    // Stage B chunk: linear 32 KB, 8 x 1KB DMA per wave.
    {
      const unsigned short* gsrc = Bt + (size_t)n0 * 256 + wave * 4096 + lane * 8;
      unsigned short* lbase = &sB[wave * 4096];
#pragma unroll
      for (int i = 0; i < 8; ++i)
        glds16(gsrc + i * 512, lbase + i * 512);
    }
    __syncthreads();   // drains the DMA (compiler emits vmcnt(0) before barrier)

#pragma unroll 1
    for (int tt = 0; tt < 4; ++tt) {
      const unsigned short* bbase = &sB[(tt * 16 + lo) * 256];
      short8 b[8];
#pragma unroll
      for (int s = 0; s < 8; ++s)
        b[s] = *reinterpret_cast<const short8*>(bbase + (((quad + s * 4) ^ sw) << 3));
      f32x4 acc = (f32x4){0.f, 0.f, 0.f, 0.f};
#pragma unroll
      for (int s = 0; s < 8; ++s)
        acc = __builtin_amdgcn_mfma_f32_16x16x32_bf16(b[s], a[s], acc, 0, 0, 0);

      const int nb = n0 + tt * 16 + quad * 4;   // this lane's 4 consecutive cols
      const int m = mrow + lo;
      if (isval) {
        const f32x4 bias4 = *reinterpret_cast<const f32x4*>(bv + nb);
        const int h = nb >> 5, d0 = nb & 31;
        if (m < M) {
          const int bb = m / LV, i = m - bb * LV;
          ushort4 o;
          o.x = (unsigned short)bf16r(acc[0] + bias4[0]);
          o.y = (unsigned short)bf16r(acc[1] + bias4[1]);
          o.z = (unsigned short)bf16r(acc[2] + bias4[2]);
          o.w = (unsigned short)bf16r(acc[3] + bias4[3]);
          *reinterpret_cast<ushort4*>(
              val + (((size_t)(bb * NH + h)) * LV + i) * D + d0) = o;
        }
      } else if (ch < 4) {                      // nb < 256: offsets -> loc
        const f32x4 bias4 = *reinterpret_cast<const f32x4*>(boff + nb);
        const int l = (nb >> 3) & 3;
        const float rsz = (l == 0) ? 0.01f : (l == 1) ? 0.02f
                        : (l == 2) ? 0.04f : (1.f / 13.f);
        if (m < M) {
          const int lr = wave * 16 + lo;        // row in sRP
          const float rx = sRP[lr][l * 2];
          const float ry = sRP[lr][l * 2 + 1];
          f32x4 o;
          o[0] = fmaf(acc[0] + bias4[0], rsz, rx);
          o[1] = fmaf(acc[1] + bias4[1], rsz, ry);
          o[2] = fmaf(acc[2] + bias4[2], rsz, rx);
          o[3] = fmaf(acc[3] + bias4[3], rsz, ry);
          *reinterpret_cast<f32x4*>(loc + (size_t)m * 256 + nb) = o;
        }
      } else {                                  // attention logits -> softmax
        const int n2 = nb - 256;                // head*16 + 4-aligned col
        const f32x4 bias4 = *reinterpret_cast<const f32x4*>(battn + n2);
        float v0 = acc[0] + bias4[0], v1 = acc[1] + bias4[1];
        float v2 = acc[2] + bias4[2], v3 = acc[3] + bias4[3];
        float mx = fmaxf(fmaxf(v0, v1), fmaxf(v2, v3));
        mx = fmaxf(mx, __shfl_xor(mx, 16, 64));
        mx = fmaxf(mx, __shfl_xor(mx, 32, 64));
        const float e0 = __expf(v0 - mx), e1 = __expf(v1 - mx);
        const float e2 = __expf(v2 - mx), e3 = __expf(v3 - mx);
        float s = e0 + e1 + e2 + e3;
        s += __shfl_xor(s, 16, 64);
        s += __shfl_xor(s, 32, 64);
        const float inv = 1.f / s;
        if (m < M) {
          f32x4 o; o[0] = e0 * inv; o[1] = e1 * inv; o[2] = e2 * inv; o[3] = e3 * inv;
          *reinterpret_cast<f32x4*>(attn + (size_t)m * 128 + n2) = o;
        }
      }
    }
  }
}

// ---------------------------------------------------------------------------
// GEMM 3 (R8 grid, R11 glds staging): out = tmp @ Wo + bo + query.
// ---------------------------------------------------------------------------
__global__ __launch_bounds__(256, 4) void k_gemm3(
    const unsigned short* __restrict__ tmp, const float* __restrict__ query,
    const unsigned short* __restrict__ Bt, const float* __restrict__ bo,
    float* __restrict__ out) {
  __shared__ unsigned short sB[64 * 256];   // 32 KB, linear (swizzled content)
  const int tid = threadIdx.x;
  const int wave = tid >> 6, lane = tid & 63, quad = lane >> 4, lo = lane & 15;
  const int m0 = blockIdx.x * 64;
  const int mrow = m0 + wave * 16;

  short8 a[8];
  {
    const int mr = min(mrow + lo, M - 1);
    load_a_bf16(tmp + (size_t)mr * 256 + quad * 8, a);
  }
  const int sw = lo & 7;

#pragma unroll 1
  for (int ch = 0; ch < 4; ++ch) {
    const int n0 = ch * 64;
    __syncthreads();
    {
      const unsigned short* gsrc = Bt + (size_t)n0 * 256 + wave * 4096 + lane * 8;
      unsigned short* lbase = &sB[wave * 4096];
#pragma unroll
      for (int i = 0; i < 8; ++i)
        glds16(gsrc + i * 512, lbase + i * 512);
    }
    __syncthreads();

#pragma unroll 1
    for (int tt = 0; tt < 4; ++tt) {
      const unsigned short* bbase = &sB[(tt * 16 + lo) * 256];
      short8 b[8];
#pragma unroll
      for (int s = 0; s < 8; ++s)
        b[s] = *reinterpret_cast<const short8*>(bbase + (((quad + s * 4) ^ sw) << 3));
      f32x4 acc = (f32x4){0.f, 0.f, 0.f, 0.f};
#pragma unroll
      for (int s = 0; s < 8; ++s)
        acc = __builtin_amdgcn_mfma_f32_16x16x32_bf16(b[s], a[s], acc, 0, 0, 0);
      const int nb = n0 + tt * 16 + quad * 4;
      const f32x4 bias4 = *reinterpret_cast<const f32x4*>(bo + nb);
      const int m = mrow + lo;
      if (m < M) {
        const int bb = m / LQ, q = m - bb * LQ;
        const size_t o = ((size_t)(q * B + bb)) * C + nb;
        const f32x4 qv = *reinterpret_cast<const f32x4*>(query + o);
        f32x4 ov;
        ov[0] = acc[0] + bias4[0] + qv[0];
        ov[1] = acc[1] + bias4[1] + qv[1];
        ov[2] = acc[2] + bias4[2] + qv[2];
        ov[3] = acc[3] + bias4[3] + qv[3];
        *reinterpret_cast<f32x4*>(out + o) = ov;
      }
    }
  }
}

// ---------------------------------------------------------------------------
// Bilinear sampling + attention weighting — EXACT R8 version (55.4 us).
// ---------------------------------------------------------------------------
#define QB_I(v, PAT) __builtin_amdgcn_ds_swizzle((v), (PAT))
#define QB_F(v, PAT) __int_as_float(__builtin_amdgcn_ds_swizzle(__float_as_int(v), (PAT)))

__device__ inline void msda_corner(f32x2 acc[4], const uint4 r, const float w) {
  const f32x2 wv = {w, w};
  f32x2 v;
  v[0] = __uint_as_float(r.x << 16);
  v[1] = __uint_as_float(r.x & 0xffff0000u);
  acc[0] = __builtin_elementwise_fma(v, wv, acc[0]);
  v[0] = __uint_as_float(r.y << 16);
  v[1] = __uint_as_float(r.y & 0xffff0000u);
  acc[1] = __builtin_elementwise_fma(v, wv, acc[1]);
  v[0] = __uint_as_float(r.z << 16);
  v[1] = __uint_as_float(r.z & 0xffff0000u);
  acc[2] = __builtin_elementwise_fma(v, wv, acc[2]);
  v[0] = __uint_as_float(r.w << 16);
  v[1] = __uint_as_float(r.w & 0xffff0000u);
  acc[3] = __builtin_elementwise_fma(v, wv, acc[3]);
}

__global__ __launch_bounds__(256, 4) void k_sample(
    const unsigned short* __restrict__ val, const float* __restrict__ loc,
    const float* __restrict__ attn, unsigned short* __restrict__ tmp) {
  constexpr int QPB = 8;
  const int mblk = blockIdx.x * QPB;
  const int t = threadIdx.x;
  __shared__ float sloc[QPB * 8 * 33];    // [q][h][33]
  __shared__ float sattn[QPB * 8 * 17];   // [q][h][17]
  for (int i = t; i < QPB * 256; i += 256) {
    int mq = mblk + (i >> 8); if (mq >= M) mq = M - 1;
    const int j = i & 255;
    sloc[(((i >> 8) << 3) + (j >> 5)) * 33 + (j & 31)] = loc[(size_t)mq * 256 + j];
  }
  for (int i = t; i < QPB * 128; i += 256) {
    int mq = mblk + (i >> 7); if (mq >= M) mq = M - 1;
    const int j = i & 127;
    sattn[(((i >> 7) << 3) + (j >> 4)) * 17 + (j & 15)] = attn[(size_t)mq * 128 + j];
  }
  __syncthreads();

  const int g = t >> 5, s = t & 31, h = s >> 2, c8 = s & 3;
  const int m = mblk + g;
  const int mc = (m < M) ? m : M - 1;
  const int b = mc / LQ;
  const unsigned short* vhead = val + ((size_t)(b * NH + h) * LV) * D + c8 * 8;
  const float* ql = sloc + (g * 8 + h) * 33;
  const float* qa = sattn + (g * 8 + h) * 17;

  f32x2 acc[4];
  acc[0] = (f32x2){0.f, 0.f}; acc[1] = (f32x2){0.f, 0.f};
  acc[2] = (f32x2){0.f, 0.f}; acc[3] = (f32x2){0.f, 0.f};
#pragma unroll 1
  for (int l = 0; l < L; ++l) {
    const int Wl = SZ[l];
    const float Wlf = (float)Wl;
    const unsigned short* vlev = vhead + (size_t)START[l] * D;
    // Own point: p = c8. (Each quad lane computes one point's geometry.)
    const float x = ql[l * 8 + c8 * 2]     * Wlf - 0.5f;
    const float y = ql[l * 8 + c8 * 2 + 1] * Wlf - 0.5f;
    const float aw = qa[l * 4 + c8];
    const float x0f = floorf(x), y0f = floorf(y);
    const float wx = x - x0f, wy = y - y0f;
    const int x0 = (int)x0f, y0 = (int)y0f;
    const int x1 = x0 + 1, y1 = y0 + 1;
    const float wy1v = wy * aw;
    const float wy0m = ((unsigned)y0 < (unsigned)Wl) ? (aw - wy1v) : 0.f;
    const float wy1m = ((unsigned)y1 < (unsigned)Wl) ? wy1v : 0.f;
    const float wx0m = ((unsigned)x0 < (unsigned)Wl) ? (1.f - wx) : 0.f;
    const float wx1m = ((unsigned)x1 < (unsigned)Wl) ? wx : 0.f;
    const int xc0 = min(max(x0, 0), Wl - 1), xc1 = min(max(x1, 0), Wl - 1);
    const int yc0 = min(max(y0, 0), Wl - 1), yc1 = min(max(y1, 0), Wl - 1);
    const int r0 = yc0 * Wl, r1 = yc1 * Wl;
    const int o00 = (r0 + xc0) * D, o01 = (r0 + xc1) * D;
    const int o10 = (r1 + xc0) * D, o11 = (r1 + xc1) * D;
    const float w00 = wy0m * wx0m, w01 = wy0m * wx1m;
    const float w10 = wy1m * wx0m, w11 = wy1m * wx1m;

    // Phase 1: broadcast all 16 offsets + weights (quad-perm).
    int   off[16];
    float ww[16];
#define MSDA_BCAST(P, PAT)                                                \
    off[(P)*4+0] = QB_I(o00, PAT); off[(P)*4+1] = QB_I(o01, PAT);         \
    off[(P)*4+2] = QB_I(o10, PAT); off[(P)*4+3] = QB_I(o11, PAT);         \
    ww[(P)*4+0]  = QB_F(w00, PAT); ww[(P)*4+1]  = QB_F(w01, PAT);         \
    ww[(P)*4+2]  = QB_F(w10, PAT); ww[(P)*4+3]  = QB_F(w11, PAT);
    MSDA_BCAST(0, 0x8000)   // p=0: sel 0,0,0,0
    MSDA_BCAST(1, 0x8055)   // p=1: sel 1,1,1,1
    MSDA_BCAST(2, 0x80AA)   // p=2: sel 2,2,2,2
    MSDA_BCAST(3, 0x80FF)   // p=3: sel 3,3,3,3
#undef MSDA_BCAST

    // Phase 2: issue all 16 gathers (stay in flight together).
    uint4 v[16];
#pragma unroll
    for (int i = 0; i < 16; ++i)
      v[i] = *reinterpret_cast<const uint4*>(vlev + off[i]);

    // Phase 3: consume in identical point/corner order.
#pragma unroll
    for (int i = 0; i < 16; ++i)
      msda_corner(acc, v[i], ww[i]);
  }
  if (m < M) {
    short8 o;
#pragma unroll
    for (int j = 0; j < 4; ++j) {
      o[2 * j]     = bf16r(acc[j][0]);
      o[2 * j + 1] = bf16r(acc[j][1]);
    }
    *reinterpret_cast<short8*>(tmp + (size_t)m * 256 + h * 32 + c8 * 8) = o;
  }
}

}  // namespace

extern "C" void kernel_launch(void* const* d_in, const int* in_sizes, int n_in,
                              void* d_out, int out_size, void* d_ws, size_t ws_size,
                              hipStream_t stream) {
  const float* query = (const float*)d_in[0];
  const float* rp    = (const float*)d_in[1];
  const float* value = (const float*)d_in[2];
  const float* Wv    = (const float*)d_in[5];
  const float* bv    = (const float*)d_in[6];
  const float* Woff  = (const float*)d_in[7];
  const float* boff  = (const float*)d_in[8];
  const float* Wattn = (const float*)d_in[9];
  const float* battn = (const float*)d_in[10];
  const float* Wo    = (const float*)d_in[11];
  const float* bo    = (const float*)d_in[12];
  float* out = (float*)d_out;

  unsigned short* Btv  = (unsigned short*)d_ws;        // 256*256
  unsigned short* Btoa = Btv + 256 * 256;              // 384*256
  unsigned short* Bto  = Btoa + 384 * 256;             // 256*256
  unsigned short* val  = Bto + 256 * 256;              // M*256 bf16
  float* loc  = (float*)(val + (size_t)M * 256);       // M*256 f32
  float* attn = loc + (size_t)M * 256;                 // M*128 f32
  unsigned short* tmp = (unsigned short*)(attn + (size_t)M * 128);  // M*256 bf16

  const int mtiles64 = (M + 63) / 64;                  // 416
  const int sample_blocks = (M + 7) / 8;               // 3324

  k_pre<<<224, 256, 0, stream>>>(Wv, Woff, Wattn, Wo, Btv, Btoa, Bto);
  k_gemm12<<<dim3(mtiles64, 2), 256, 0, stream>>>(query, value, rp, Btv, Btoa,
                                                  bv, boff, battn, val, loc, attn);
  k_sample<<<sample_blocks, 256, 0, stream>>>(val, loc, attn, tmp);
  k_gemm3<<<mtiles64, 256, 0, stream>>>(tmp, query, Bto, bo, out);
}